// Round 3
// baseline (177.349 us; speedup 1.0000x reference)
//
#include <hip/hip_runtime.h>

// GCN layer: out = (D^-1/2 (A+I) D^-1/2) X W^T + b
// N=100000, E=1600000, D=64.
//
// Round 14: counters show all our kernels < 44.3us; top-5 is the harness's
// 256MB workspace re-poison fill (44.5us/iter, fixed cost). Of our ~80us:
// scatter ~12, gemm ~33-40 (only 23TF = 15% fp32 peak, VALUBusy 22%),
// gather ~30 (near its L3-random-row ceiling). This round targets the
// gemm only: 128x64 tiles (782 blocks, was 1563):
//   - each thread: 8x4 acc -> 32 FMA per 3 ds_read_b128 (was 16 per 2)
//   - W staged 782x instead of 1563x (halves redundant L2 traffic + instrs)
//   - per-block fixed costs (syncs, hist setup, epilogue) amortized 2x
//   - tile spans 2 buckets; deg hist covers lh[128] from 2 grec regions
// Same accumulation order + f2b_rn rounding point -> bit-identical output.
//
// Pipeline (4 dispatches):
//   D0 memset gcur (6KB)
//   D1 scatter: bin edges into fixed-capacity bucket regions
//   D2 gemm_scaled: per-tile LDS deg hist + xW^T + bf16(acc*rsqrt(deg+1))
//   D3 csr_gather: per-bucket LDS sort + gather pre-scaled rows + bias

#define BSHIFT 6
#define BNODES 64
#define CAP 1536      // records per bucket (mean 1024, +16 sigma)
#define EPB 4096      // edges per scatter block -> 391 blocks
#define NBUCK_PAD 1568  // >= nbuck (1563), for static smem carve

__device__ inline unsigned short f2b_rn(float f) {
    unsigned u = __float_as_uint(f);
    unsigned r = u + 0x7FFFu + ((u >> 16) & 1u);
    return (unsigned short)(r >> 16);
}
__device__ inline float b2f(unsigned short h) {
    return __uint_as_float(((unsigned)h) << 16);
}

// --- D1: binned scatter into fixed-capacity bucket regions ---
__global__ __launch_bounds__(256) void scatter_kernel(
    const int* __restrict__ ei, int* __restrict__ gcur,
    unsigned int* __restrict__ grec, int e, int nbuck) {
    __shared__ unsigned int lrec[EPB];       // 16384 B
    __shared__ unsigned short lbk[EPB];      //  8192 B
    __shared__ int lh[NBUCK_PAD];            //  6272 B
    __shared__ int lbase[NBUCK_PAD];         //  6272 B
    int t = threadIdx.x;
    for (int i = t; i < nbuck; i += 256) lh[i] = 0;
    __syncthreads();
    int e0 = blockIdx.x * EPB;
    int m = e - e0;
    if (m > EPB) m = EPB;
    for (int i = t; i < m; i += 256) {
        int g = e0 + i;
        int s = ei[g];
        int d = ei[e + g];
        int b = d >> BSHIFT;
        lrec[i] = ((unsigned int)s << BSHIFT) | (unsigned int)(d & (BNODES - 1));
        lbk[i] = (unsigned short)b;
        atomicAdd(&lh[b], 1);
    }
    __syncthreads();
    for (int b = t; b < nbuck; b += 256) {
        int c = lh[b];
        lbase[b] = c ? atomicAdd(&gcur[b], c) : 0;
        lh[b] = 0;  // reuse as local cursor
    }
    __syncthreads();
    for (int i = t; i < m; i += 256) {
        int b = lbk[i];
        int pos = lbase[b] + atomicAdd(&lh[b], 1);
        if (pos < CAP)
            grec[(size_t)b * CAP + pos] = lrec[i];
    }
}

// --- D2: 128x64 tile gemm + per-tile deg hist + scaled bf16 out ---
// Block b handles rows [128b, 128b+128) = buckets {2b, 2b+1}.
__global__ __launch_bounds__(256) void gemm_scaled_kernel(
    const float* __restrict__ x, const float* __restrict__ W,
    ushort4* __restrict__ yh,
    const unsigned int* __restrict__ grec, const int* __restrict__ gcur,
    int n, int nbuck) {
    __shared__ __align__(16) float4 At4[2048];  // [64k][32rq] swz: At4[k*32+(rq^(k&31))]
    __shared__ __align__(16) float4 Wt4[1024];  // [64k][16rq] swz: Wt4[k*16+(r^(k&15))]
    __shared__ int lh[128];
    int t = threadIdx.x;
    int b = blockIdx.x;
    int m0 = b << 7;  // 128 rows per tile

    if (t < 128) lh[t] = 0;
    __syncthreads();

    // deg hist for the tile's two buckets (grec regions L2/L3-hot)
#pragma unroll
    for (int rb = 0; rb < 2; ++rb) {
        int bk = 2 * b + rb;
        if (bk < nbuck) {
            size_t base = (size_t)bk * CAP;
            int cnt = gcur[bk];
            if (cnt > CAP) cnt = CAP;
            for (int i = t; i < cnt; i += 256)
                atomicAdd(&lh[(rb << 6) + (grec[base + i] & (BNODES - 1))], 1);
        }
    }

    // stage W tile (1024 quads, 4 iters)
#pragma unroll
    for (int j = 0; j < 4; ++j) {
        int idx = t + j * 256;      // 0..1023
        int k = idx & 63;           // lane-consecutive -> coalesced global
        int r = idx >> 6;           // quad row 0..15
        float4 wv;
        wv.x = W[(size_t)(4 * r + 0) * 64 + k];
        wv.y = W[(size_t)(4 * r + 1) * 64 + k];
        wv.z = W[(size_t)(4 * r + 2) * 64 + k];
        wv.w = W[(size_t)(4 * r + 3) * 64 + k];
        Wt4[k * 16 + (r ^ (k & 15))] = wv;
    }
    // stage A tile (2048 quads, 8 iters)
#pragma unroll
    for (int j = 0; j < 8; ++j) {
        int idx = t + j * 256;      // 0..2047
        int k = idx & 63;
        int rq = idx >> 6;          // quad row 0..31
        float4 av;
        int gm = m0 + 4 * rq;
        av.x = (gm + 0 < n) ? x[(size_t)(gm + 0) * 64 + k] : 0.f;
        av.y = (gm + 1 < n) ? x[(size_t)(gm + 1) * 64 + k] : 0.f;
        av.z = (gm + 2 < n) ? x[(size_t)(gm + 2) * 64 + k] : 0.f;
        av.w = (gm + 3 < n) ? x[(size_t)(gm + 3) * 64 + k] : 0.f;
        At4[k * 32 + (rq ^ (k & 31))] = av;
    }
    __syncthreads();

    int tx = t & 15, ty = t >> 4;  // tx: out quad (4 cols), ty: 8-row group
    float acc[8][4];
#pragma unroll
    for (int i = 0; i < 8; ++i)
#pragma unroll
        for (int j = 0; j < 4; ++j) acc[i][j] = 0.f;

#pragma unroll 4
    for (int k = 0; k < 64; ++k) {
        float4 a0 = At4[k * 32 + ((2 * ty + 0) ^ (k & 31))];  // rows 8ty..+3
        float4 a1 = At4[k * 32 + ((2 * ty + 1) ^ (k & 31))];  // rows 8ty+4..+7
        float4 w = Wt4[k * 16 + (tx ^ (k & 15))];             // cols 4tx..+3
        float av[8] = {a0.x, a0.y, a0.z, a0.w, a1.x, a1.y, a1.z, a1.w};
        float wv[4] = {w.x, w.y, w.z, w.w};
#pragma unroll
        for (int i = 0; i < 8; ++i)
#pragma unroll
            for (int j = 0; j < 4; ++j) acc[i][j] += av[i] * wv[j];
    }

    // epilogue: src-side normalization from LDS deg + bf16 pack
#pragma unroll
    for (int i = 0; i < 8; ++i) {
        int lr = ty * 8 + i;        // local row 0..127
        int gm = m0 + lr;
        if (gm < n) {
            float dn = rsqrtf((float)(lh[lr] + 1));  // +1 self loop
            ushort4 h;
            h.x = f2b_rn(acc[i][0] * dn);
            h.y = f2b_rn(acc[i][1] * dn);
            h.z = f2b_rn(acc[i][2] * dn);
            h.w = f2b_rn(acc[i][3] * dn);
            yh[(size_t)gm * 16 + tx] = h;
        }
    }
}

// --- D3: per-bucket fused sort + gather (1563 x 256thr, fully resident) ---
__global__ __launch_bounds__(256, 8) void csr_gather_kernel(
    const unsigned int* __restrict__ grec, const int* __restrict__ gcur,
    const ushort4* __restrict__ yh, const float* __restrict__ bias,
    float4* __restrict__ out, int n) {
    __shared__ unsigned int sorted[CAP];  // 6144 B: src ids grouped by dst
    __shared__ int lh[BNODES];            // hist, then cursor
    __shared__ int ls[BNODES + 1];        // exclusive offsets; ls[64] = cnt
    int t = threadIdx.x;
    int b = blockIdx.x;
    size_t base = (size_t)b * CAP;
    int cnt = gcur[b];
    if (cnt > CAP) cnt = CAP;
    int node0 = b << BSHIFT;

    if (t < BNODES) lh[t] = 0;
    __syncthreads();
    for (int i = t; i < cnt; i += 256)
        atomicAdd(&lh[grec[base + i] & (BNODES - 1)], 1);
    __syncthreads();
    if (t < BNODES) {  // wave 0: inclusive shfl scan over 64 bins
        int c = lh[t];
        int v = c;
#pragma unroll
        for (int o = 1; o < 64; o <<= 1) {
            int u = __shfl_up(v, o, 64);
            if (t >= o) v += u;
        }
        ls[t] = v - c;
        lh[t] = 0;  // cursor
        if (t == 63) ls[BNODES] = v;
    }
    __syncthreads();
    for (int i = t; i < cnt; i += 256) {  // re-read grec (L2-hot), sort into LDS
        unsigned int r = grec[base + i];
        int nd = r & (BNODES - 1);
        int pos = ls[nd] + atomicAdd(&lh[nd], 1);
        sorted[pos] = r >> BSHIFT;
    }
    __syncthreads();

    // ---- gather: wave w handles nodes [w*16, w*16+16) of this bucket ----
    int wave = t >> 6;
    int lane = t & 63;
    int grp = lane >> 4;   // which of 4 concurrent edges
    int fq = lane & 15;    // feature quad
    float4 bb = ((const float4*)bias)[fq];
    for (int i = 0; i < 16; ++i) {
        int nd = wave * 16 + i;
        int node = node0 + nd;
        if (node >= n) break;  // uniform per wave
        int beg = ls[nd];
        int end = ls[nd + 1];
        float dn = rsqrtf((float)(end - beg) + 1.0f);  // deg+1 (self loop)
        float4 acc = {0.f, 0.f, 0.f, 0.f};
        if (grp == 0) {  // self loop term y'_self
            ushort4 h = yh[(size_t)node * 16 + fq];
            acc.x = b2f(h.x); acc.y = b2f(h.y);
            acc.z = b2f(h.z); acc.w = b2f(h.w);
        }
        int j = beg + grp;
        // 4x unrolled: four independent row loads in flight per iteration
        for (; j + 12 < end; j += 16) {
            int s0 = (int)sorted[j];
            int s1 = (int)sorted[j + 4];
            int s2 = (int)sorted[j + 8];
            int s3 = (int)sorted[j + 12];
            ushort4 h0 = yh[(size_t)s0 * 16 + fq];  // 128B rows
            ushort4 h1 = yh[(size_t)s1 * 16 + fq];
            ushort4 h2 = yh[(size_t)s2 * 16 + fq];
            ushort4 h3 = yh[(size_t)s3 * 16 + fq];
            acc.x += b2f(h0.x) + b2f(h1.x) + b2f(h2.x) + b2f(h3.x);
            acc.y += b2f(h0.y) + b2f(h1.y) + b2f(h2.y) + b2f(h3.y);
            acc.z += b2f(h0.z) + b2f(h1.z) + b2f(h2.z) + b2f(h3.z);
            acc.w += b2f(h0.w) + b2f(h1.w) + b2f(h2.w) + b2f(h3.w);
        }
        for (; j < end; j += 4) {  // tail, one per group-stride
            int s = (int)sorted[j];
            ushort4 h = yh[(size_t)s * 16 + fq];
            acc.x += b2f(h.x); acc.y += b2f(h.y);
            acc.z += b2f(h.z); acc.w += b2f(h.w);
        }
        for (int m = 16; m < 64; m <<= 1) {  // reduce 4 edge-groups
            acc.x += __shfl_xor(acc.x, m);
            acc.y += __shfl_xor(acc.y, m);
            acc.z += __shfl_xor(acc.z, m);
            acc.w += __shfl_xor(acc.w, m);
        }
        if (lane < 16) {
            float4 o;
            o.x = acc.x * dn + bb.x;
            o.y = acc.y * dn + bb.y;
            o.z = acc.z * dn + bb.z;
            o.w = acc.w * dn + bb.w;
            out[(size_t)node * 16 + lane] = o;
        }
    }
}

extern "C" void kernel_launch(void* const* d_in, const int* in_sizes, int n_in,
                              void* d_out, int out_size, void* d_ws, size_t ws_size,
                              hipStream_t stream) {
    const float* x    = (const float*)d_in[0];
    const int*   ei   = (const int*)d_in[1];  // [2,E]: src row then dst row
    const float* W    = (const float*)d_in[2];
    const float* bias = (const float*)d_in[3];
    float* out = (float*)d_out;

    int n = in_sizes[0] / 64;
    int e = in_sizes[1] / 2;
    int nbuck = (n + BNODES - 1) / BNODES;  // 1563 (<= NBUCK_PAD)

    // workspace (256B aligned): gcur | grec | yh  (~23 MB)
    auto align = [](size_t v) { return (v + 255) & ~(size_t)255; };
    char* p = (char*)d_ws;
    int* gcur = (int*)p;                    p += align((size_t)nbuck * 4);
    unsigned int* grec = (unsigned int*)p;  p += align((size_t)nbuck * CAP * 4);
    ushort4* yh = (ushort4*)p;

    int sblocks = (e + EPB - 1) / EPB;     // 391
    int tblocks = (n + 127) / 128;         // 782 gemm tiles

    hipMemsetAsync(gcur, 0, (size_t)nbuck * 4, stream);
    scatter_kernel<<<sblocks, 256, 0, stream>>>(ei, gcur, grec, e, nbuck);
    gemm_scaled_kernel<<<tblocks, 256, 0, stream>>>(x, W, yh, grec, gcur, n, nbuck);
    csr_gather_kernel<<<nbuck, 256, 0, stream>>>(grec, gcur, yh, bias,
                                                 (float4*)out, n);
}

// Round 4
// 165.898 us; speedup vs baseline: 1.0690x; 1.0690x over previous
//
#include <hip/hip_runtime.h>

// GCN layer: out = (D^-1/2 (A+I) D^-1/2) X W^T + b
// N=100000, E=1600000, D=64.
//
// Round 15: post-mortem r13/r14 -- serializing scatter(13us)+gemm(45us)
// cost ~58us where r0's fused concurrent dispatch did both in 44.4us
// (scatter is memory/atomic-bound, gemm is VALU/latency-bound; they
// co-schedule). The serialization existed only because the gemm epilogue
// needed deg (from scatter). Fix: move src-side normalization OUT of the
// gemm into the gather:
//   - fused scatter || PURE gemm writing unnormalized yh = bf16(xW^T)
//     (no hist, no deg; bf16 stores halve its write traffic vs r0)
//   - tiny dnorm kernel: per-bucket hist of L2-hot grec ->
//     dnorm[node] = rsqrt(deg+1)  (400KB table, ~4us)
//   - gather: acc += dnorm[src] * b2f(row)  (add -> fma, same VALU count;
//     +1 L2-hot 4B load per edge); dst-side scale from its own CSR as
//     before. Same dispatch count (4).
//
// Pipeline:
//   D0 memset gcur (3KB)
//   D1 fused: gemm yh=bf16(xW^T) || binned scatter
//   D2 dnorm: per-bucket LDS hist -> rsqrt(deg+1) table
//   D3 csr_gather: per-bucket LDS sort + dnorm-weighted gather + bias

#define BSHIFT 7
#define BNODES 128
#define CAP 3072   // records per bucket region (mean 2046, P(overflow)~1e-90)
#define EPB 4096   // edges per scatter block -> 391 blocks
#define SMEM_BYTES 32768  // max(gemm 32768, scatter 24576+nbuck*8<=30832)

__device__ inline unsigned short f2b_rn(float f) {
    unsigned u = __float_as_uint(f);
    unsigned r = u + 0x7FFFu + ((u >> 16) & 1u);
    return (unsigned short)(r >> 16);
}
__device__ inline float b2f(unsigned short h) {
    return __uint_as_float(((unsigned)h) << 16);
}

// --- D1: fused gemm || scatter (independent work, one dispatch) ---
__global__ __launch_bounds__(256) void fused_gemm_scatter_kernel(
    const float* __restrict__ x, const float* __restrict__ W,
    ushort4* __restrict__ yh,
    const int* __restrict__ ei, int* __restrict__ gcur,
    unsigned int* __restrict__ grec,
    int n, int e, int nbuck, int sblocks) {
    __shared__ __align__(16) unsigned char smem[SMEM_BYTES];
    int t = threadIdx.x;

    if ((int)blockIdx.x < sblocks) {
        // ---- binned scatter into fixed-capacity bucket regions ----
        unsigned int* lrec = (unsigned int*)smem;               // EPB*4 = 16384
        unsigned short* lbk = (unsigned short*)(smem + 16384);  // EPB*2 = 8192
        int* lh = (int*)(smem + 24576);                         // [nbuck]
        int* lbase = lh + nbuck;                                // [nbuck]
        for (int i = t; i < nbuck; i += 256) lh[i] = 0;
        __syncthreads();
        int e0 = blockIdx.x * EPB;
        int m = e - e0;
        if (m > EPB) m = EPB;
        for (int i = t; i < m; i += 256) {
            int g = e0 + i;
            int s = ei[g];
            int d = ei[e + g];
            int b = d >> BSHIFT;
            lrec[i] = ((unsigned int)s << BSHIFT) | (unsigned int)(d & (BNODES - 1));
            lbk[i] = (unsigned short)b;
            atomicAdd(&lh[b], 1);
        }
        __syncthreads();
        for (int b = t; b < nbuck; b += 256) {
            int c = lh[b];
            lbase[b] = c ? atomicAdd(&gcur[b], c) : 0;
            lh[b] = 0;  // reuse as local cursor
        }
        __syncthreads();
        for (int i = t; i < m; i += 256) {
            int b = lbk[i];
            int pos = lbase[b] + atomicAdd(&lh[b], 1);
            if (pos < CAP)
                grec[(size_t)b * CAP + pos] = lrec[i];
        }
    } else {
        // ---- pure gemm: yh = bf16(x @ W^T); XOR-swizzled float4 LDS tiles --
        float4* At4 = (float4*)smem;             // [64*16] At4[k*16 + (r^(k&15))] = A[4r..+3][k]
        float4* Wt4 = (float4*)(smem + 16384);   // [64*16] same layout for W
        int m0 = ((int)blockIdx.x - sblocks) * 64;

#pragma unroll
        for (int j = 0; j < 4; ++j) {
            int idx = t + j * 256;      // 0..1023
            int k = idx & 63;           // lane-consecutive -> coalesced global
            int r = idx >> 6;           // quad row index 0..15
            // W tile: rows 4r..4r+3 at col k
            float4 wv;
            wv.x = W[(size_t)(4 * r + 0) * 64 + k];
            wv.y = W[(size_t)(4 * r + 1) * 64 + k];
            wv.z = W[(size_t)(4 * r + 2) * 64 + k];
            wv.w = W[(size_t)(4 * r + 3) * 64 + k];
            Wt4[k * 16 + (r ^ (k & 15))] = wv;
            // A tile: rows m0+4r..+3 at col k (guarded)
            float4 av;
            int gm = m0 + 4 * r;
            av.x = (gm + 0 < n) ? x[(size_t)(gm + 0) * 64 + k] : 0.f;
            av.y = (gm + 1 < n) ? x[(size_t)(gm + 1) * 64 + k] : 0.f;
            av.z = (gm + 2 < n) ? x[(size_t)(gm + 2) * 64 + k] : 0.f;
            av.w = (gm + 3 < n) ? x[(size_t)(gm + 3) * 64 + k] : 0.f;
            At4[k * 16 + (r ^ (k & 15))] = av;
        }
        __syncthreads();

        int tx = t & 15, ty = t >> 4;  // tx: out quad, ty: row quad
        float acc[4][4];
#pragma unroll
        for (int i = 0; i < 4; ++i)
#pragma unroll
            for (int j = 0; j < 4; ++j) acc[i][j] = 0.f;

#pragma unroll 8
        for (int k = 0; k < 64; ++k) {
            float4 a = At4[k * 16 + (ty ^ (k & 15))];  // rows ty*4..+3 @ k (broadcast)
            float4 w = Wt4[k * 16 + (tx ^ (k & 15))];  // cols tx*4..+3 @ k
            float av[4] = {a.x, a.y, a.z, a.w};
            float wv[4] = {w.x, w.y, w.z, w.w};
#pragma unroll
            for (int i = 0; i < 4; ++i)
#pragma unroll
                for (int j = 0; j < 4; ++j) acc[i][j] += av[i] * wv[j];
        }

        // epilogue: straight bf16 pack (normalization deferred to gather)
#pragma unroll
        for (int i = 0; i < 4; ++i) {
            int gm = m0 + ty * 4 + i;
            if (gm < n) {
                ushort4 h;
                h.x = f2b_rn(acc[i][0]);
                h.y = f2b_rn(acc[i][1]);
                h.z = f2b_rn(acc[i][2]);
                h.w = f2b_rn(acc[i][3]);
                yh[(size_t)gm * 16 + tx] = h;
            }
        }
    }
}

// --- D2: per-bucket deg hist -> dnorm[node] = rsqrt(deg+1) (400KB table) ---
__global__ __launch_bounds__(256) void dnorm_kernel(
    const unsigned int* __restrict__ grec, const int* __restrict__ gcur,
    float* __restrict__ dnorm, int n) {
    __shared__ int lh[BNODES];
    int t = threadIdx.x;
    int b = blockIdx.x;
    size_t base = (size_t)b * CAP;
    int cnt = gcur[b];
    if (cnt > CAP) cnt = CAP;
    if (t < BNODES) lh[t] = 0;
    __syncthreads();
    for (int i = t; i < cnt; i += 256)
        atomicAdd(&lh[grec[base + i] & (BNODES - 1)], 1);
    __syncthreads();
    if (t < BNODES) {
        int node = (b << BSHIFT) + t;
        if (node < n) dnorm[node] = rsqrtf((float)lh[t] + 1.0f);
    }
}

// --- D3: per-bucket fused sort + dnorm-weighted gather (782 x 512thr) ---
__global__ __launch_bounds__(512, 4) void csr_gather_kernel(
    const unsigned int* __restrict__ grec, const int* __restrict__ gcur,
    const ushort4* __restrict__ yh, const float* __restrict__ dnorm,
    const float* __restrict__ bias,
    float4* __restrict__ out, int n) {
    __shared__ unsigned int sorted[CAP];  // 12288 B: src ids grouped by dst
    __shared__ int lh[BNODES];            // hist, then cursor
    __shared__ int ls[BNODES + 1];        // exclusive offsets; ls[128] = cnt
    __shared__ int wtot;
    int t = threadIdx.x;
    int b = blockIdx.x;
    size_t base = (size_t)b * CAP;
    int cnt = gcur[b];
    if (cnt > CAP) cnt = CAP;
    int node0 = b << BSHIFT;

    if (t < BNODES) lh[t] = 0;
    __syncthreads();
    for (int i = t; i < cnt; i += 512)
        atomicAdd(&lh[grec[base + i] & (BNODES - 1)], 1);
    __syncthreads();
    int c = 0, ex = 0;
    if (t < BNODES) {  // waves 0,1: inclusive shfl scan over 128 bins
        c = lh[t];
        int lane64 = t & 63;
        int v = c;
#pragma unroll
        for (int o = 1; o < 64; o <<= 1) {
            int u = __shfl_up(v, o, 64);
            if (lane64 >= o) v += u;
        }
        if (t == 63) wtot = v;
        ex = v - c;
    }
    __syncthreads();
    if (t >= 64 && t < BNODES) ex += wtot;
    if (t < BNODES) {
        ls[t] = ex;
        lh[t] = 0;  // cursor
        if (t == BNODES - 1) ls[BNODES] = ex + c;
    }
    __syncthreads();
    for (int i = t; i < cnt; i += 512) {  // re-read grec (L2-hot), sort into LDS
        unsigned int r = grec[base + i];
        int nd = r & (BNODES - 1);
        int pos = ls[nd] + atomicAdd(&lh[nd], 1);
        sorted[pos] = r >> BSHIFT;
    }
    __syncthreads();

    // ---- gather: wave w handles nodes [w*16, w*16+16) of this bucket ----
    int wave = t >> 6;
    int lane = t & 63;
    int grp = lane >> 4;   // which of 4 concurrent edges
    int fq = lane & 15;    // feature quad
    float4 bb = ((const float4*)bias)[fq];
    for (int i = 0; i < 16; ++i) {
        int nd = wave * 16 + i;
        int node = node0 + nd;
        if (node >= n) break;  // uniform per wave
        int beg = ls[nd];
        int end = ls[nd + 1];
        float dn = rsqrtf((float)(end - beg) + 1.0f);  // deg+1 (self loop)
        float4 acc = {0.f, 0.f, 0.f, 0.f};
        if (grp == 0) {  // self loop term: dn_self == dn (same node)
            ushort4 h = yh[(size_t)node * 16 + fq];
            acc.x = dn * b2f(h.x); acc.y = dn * b2f(h.y);
            acc.z = dn * b2f(h.z); acc.w = dn * b2f(h.w);
        }
        int j = beg + grp;
        // 4x unrolled: four independent row loads in flight per iteration
        for (; j + 12 < end; j += 16) {
            int s0 = (int)sorted[j];
            int s1 = (int)sorted[j + 4];
            int s2 = (int)sorted[j + 8];
            int s3 = (int)sorted[j + 12];
            ushort4 h0 = yh[(size_t)s0 * 16 + fq];  // 128B rows
            ushort4 h1 = yh[(size_t)s1 * 16 + fq];
            ushort4 h2 = yh[(size_t)s2 * 16 + fq];
            ushort4 h3 = yh[(size_t)s3 * 16 + fq];
            float d0 = dnorm[s0];                   // L2-hot 400KB table
            float d1 = dnorm[s1];
            float d2 = dnorm[s2];
            float d3 = dnorm[s3];
            acc.x += d0 * b2f(h0.x); acc.x += d1 * b2f(h1.x);
            acc.x += d2 * b2f(h2.x); acc.x += d3 * b2f(h3.x);
            acc.y += d0 * b2f(h0.y); acc.y += d1 * b2f(h1.y);
            acc.y += d2 * b2f(h2.y); acc.y += d3 * b2f(h3.y);
            acc.z += d0 * b2f(h0.z); acc.z += d1 * b2f(h1.z);
            acc.z += d2 * b2f(h2.z); acc.z += d3 * b2f(h3.z);
            acc.w += d0 * b2f(h0.w); acc.w += d1 * b2f(h1.w);
            acc.w += d2 * b2f(h2.w); acc.w += d3 * b2f(h3.w);
        }
        for (; j < end; j += 4) {  // tail, one per group-stride
            int s = (int)sorted[j];
            ushort4 h = yh[(size_t)s * 16 + fq];
            float d0 = dnorm[s];
            acc.x += d0 * b2f(h.x); acc.y += d0 * b2f(h.y);
            acc.z += d0 * b2f(h.z); acc.w += d0 * b2f(h.w);
        }
        for (int m = 16; m < 64; m <<= 1) {  // reduce 4 edge-groups
            acc.x += __shfl_xor(acc.x, m);
            acc.y += __shfl_xor(acc.y, m);
            acc.z += __shfl_xor(acc.z, m);
            acc.w += __shfl_xor(acc.w, m);
        }
        if (lane < 16) {
            float4 o;
            o.x = acc.x * dn + bb.x;
            o.y = acc.y * dn + bb.y;
            o.z = acc.z * dn + bb.z;
            o.w = acc.w * dn + bb.w;
            out[(size_t)node * 16 + lane] = o;
        }
    }
}

extern "C" void kernel_launch(void* const* d_in, const int* in_sizes, int n_in,
                              void* d_out, int out_size, void* d_ws, size_t ws_size,
                              hipStream_t stream) {
    const float* x    = (const float*)d_in[0];
    const int*   ei   = (const int*)d_in[1];  // [2,E]: src row then dst row
    const float* W    = (const float*)d_in[2];
    const float* bias = (const float*)d_in[3];
    float* out = (float*)d_out;

    int n = in_sizes[0] / 64;
    int e = in_sizes[1] / 2;
    int nbuck = (n + BNODES - 1) / BNODES;  // 782 (<=1024 for scatter smem carve)

    // workspace (256B aligned): gcur | grec | dnorm | yh  (~23 MB)
    auto align = [](size_t v) { return (v + 255) & ~(size_t)255; };
    char* p = (char*)d_ws;
    int* gcur = (int*)p;                    p += align((size_t)nbuck * 4);
    unsigned int* grec = (unsigned int*)p;  p += align((size_t)nbuck * CAP * 4);
    float* dnorm = (float*)p;               p += align((size_t)n * 4);
    ushort4* yh = (ushort4*)p;

    int sblocks = (e + EPB - 1) / EPB;   // 391
    int gblocks = (n + 63) / 64;         // 1563 gemm tiles

    hipMemsetAsync(gcur, 0, (size_t)nbuck * 4, stream);
    fused_gemm_scatter_kernel<<<sblocks + gblocks, 256, 0, stream>>>(
        x, W, yh, ei, gcur, grec, n, e, nbuck, sblocks);
    dnorm_kernel<<<nbuck, 256, 0, stream>>>(grec, gcur, dnorm, n);
    csr_gather_kernel<<<nbuck, 512, 0, stream>>>(grec, gcur, yh, dnorm, bias,
                                                 (float4*)out, n);
}

// Round 5
// 163.204 us; speedup vs baseline: 1.0867x; 1.0165x over previous
//
#include <hip/hip_runtime.h>

// GCN layer: out = (D^-1/2 (A+I) D^-1/2) X W^T + b
// N=100000, E=1600000, D=64.
//
// Round 16: replace the fused kernel's fp32 VALU gemm (23TF, 15% of fp32
// peak, 1024 v_fma/thread, VALUBusy 22%) with split-bf16 MFMA emulation:
//   x = x_hi + x_lo, W = w_hi + w_lo (truncated bf16 + bf16 residual);
//   y = x_lo*w_hi + x_hi*w_lo + x_hi*w_hi via 3 chained
//   v_mfma_f32_16x16x32_bf16 (fp32 accumulate). Dropped lo*lo term is
//   <= 2^-14 * sum|xw| ~ 1e-4 = 3% of the bf16 yh quantum -> absmax
//   unchanged. Operand order mfma(W, x): A-frag = W[16o x 32k] row-major
//   16B/lane, B-frag = x[32k x 16node] row-major 16B/lane -- both direct
//   global loads, no LDS/sync/transpose in the gemm branch; D lane
//   layout (col=node, row=4 consecutive o's per reg) maps each lane's
//   f32x4 acc onto exactly one ushort4 yh store.
// Per wave: ~320 VALU + 24 MFMA + 20 dwordx4 vs 2048 FMA-cycles before;
// gemm becomes memory-bound (~6us for x's 25.6MB) and the fused dispatch
// collapses toward the scatter's ~13-15us.
//
// Pipeline:
//   D0 memset gcur (3KB)
//   D1 fused: gemm yh=bf16(xW^T) (MFMA) || binned scatter
//   D2 dnorm: per-bucket LDS hist -> rsqrt(deg+1) table
//   D3 csr_gather: per-bucket LDS sort + dnorm-weighted gather + bias

#define BSHIFT 7
#define BNODES 128
#define CAP 3072   // records per bucket region (mean 2046, P(overflow)~1e-90)
#define EPB 4096   // edges per scatter block -> 391 blocks
#define SMEM_BYTES 32768  // scatter: 24576 + nbuck*8 <= 30832

typedef short bf16x8 __attribute__((ext_vector_type(8)));
typedef float f32x4 __attribute__((ext_vector_type(4)));

__device__ inline unsigned short f2b_rn(float f) {
    unsigned u = __float_as_uint(f);
    unsigned r = u + 0x7FFFu + ((u >> 16) & 1u);
    return (unsigned short)(r >> 16);
}
__device__ inline float b2f(unsigned short h) {
    return __uint_as_float(((unsigned)h) << 16);
}

// split 8 fp32 (two float4) into hi (truncated bf16) + lo (bf16 of residual)
__device__ inline void split8(float4 a, float4 b, bf16x8* hi, bf16x8* lo) {
    float f[8] = {a.x, a.y, a.z, a.w, b.x, b.y, b.z, b.w};
    union U { unsigned u[4]; bf16x8 v; } uh, ul;
#pragma unroll
    for (int i = 0; i < 4; ++i) {
        unsigned u0 = __float_as_uint(f[2 * i]);
        unsigned u1 = __float_as_uint(f[2 * i + 1]);
        uh.u[i] = (u0 >> 16) | (u1 & 0xFFFF0000u);
        float r0 = f[2 * i]     - __uint_as_float(u0 & 0xFFFF0000u);
        float r1 = f[2 * i + 1] - __uint_as_float(u1 & 0xFFFF0000u);
        unsigned v0 = __float_as_uint(r0);
        unsigned v1 = __float_as_uint(r1);
        ul.u[i] = (v0 >> 16) | (v1 & 0xFFFF0000u);
    }
    *hi = uh.v;
    *lo = ul.v;
}

// --- D1: fused gemm (MFMA) || scatter (independent work, one dispatch) ---
__global__ __launch_bounds__(256) void fused_gemm_scatter_kernel(
    const float* __restrict__ x, const float* __restrict__ W,
    ushort4* __restrict__ yh,
    const int* __restrict__ ei, int* __restrict__ gcur,
    unsigned int* __restrict__ grec,
    int n, int e, int nbuck, int sblocks) {
    __shared__ __align__(16) unsigned char smem[SMEM_BYTES];
    int t = threadIdx.x;

    if ((int)blockIdx.x < sblocks) {
        // ---- binned scatter into fixed-capacity bucket regions ----
        unsigned int* lrec = (unsigned int*)smem;               // EPB*4 = 16384
        unsigned short* lbk = (unsigned short*)(smem + 16384);  // EPB*2 = 8192
        int* lh = (int*)(smem + 24576);                         // [nbuck]
        int* lbase = lh + nbuck;                                // [nbuck]
        for (int i = t; i < nbuck; i += 256) lh[i] = 0;
        __syncthreads();
        int e0 = blockIdx.x * EPB;
        int m = e - e0;
        if (m > EPB) m = EPB;
        for (int i = t; i < m; i += 256) {
            int g = e0 + i;
            int s = ei[g];
            int d = ei[e + g];
            int b = d >> BSHIFT;
            lrec[i] = ((unsigned int)s << BSHIFT) | (unsigned int)(d & (BNODES - 1));
            lbk[i] = (unsigned short)b;
            atomicAdd(&lh[b], 1);
        }
        __syncthreads();
        for (int b = t; b < nbuck; b += 256) {
            int c = lh[b];
            lbase[b] = c ? atomicAdd(&gcur[b], c) : 0;
            lh[b] = 0;  // reuse as local cursor
        }
        __syncthreads();
        for (int i = t; i < m; i += 256) {
            int b = lbk[i];
            int pos = lbase[b] + atomicAdd(&lh[b], 1);
            if (pos < CAP)
                grec[(size_t)b * CAP + pos] = lrec[i];
        }
    } else {
        // ---- gemm: yh = bf16(x @ W^T) via split-bf16 MFMA ----
        // wave handles 16 nodes x all 64 output dims
        int wave = t >> 6, lane = t & 63;
        int jn = lane & 15;      // node within wave tile (B-frag / D col)
        int g = lane >> 4;       // k-subgroup: elements k = 8g..8g+7 (+32*kb)
        int node = ((int)blockIdx.x - sblocks) * 64 + wave * 16 + jn;

        // x fragments: hi/lo for kb=0,1
        bf16x8 xhi[2], xlo[2];
#pragma unroll
        for (int kb = 0; kb < 2; ++kb) {
            float4 p0 = {0.f, 0.f, 0.f, 0.f}, p1 = {0.f, 0.f, 0.f, 0.f};
            if (node < n) {
                const float4* xp =
                    (const float4*)(x + (size_t)node * 64 + kb * 32 + g * 8);
                p0 = xp[0];
                p1 = xp[1];
            }
            split8(p0, p1, &xhi[kb], &xlo[kb]);
        }

        // loop over 4 output-dim tiles (o = 16t .. 16t+15)
#pragma unroll
        for (int tt = 0; tt < 4; ++tt) {
            f32x4 acc = {0.f, 0.f, 0.f, 0.f};
#pragma unroll
            for (int kb = 0; kb < 2; ++kb) {
                const float4* wp =
                    (const float4*)(W + (size_t)(tt * 16 + jn) * 64 + kb * 32 + g * 8);
                float4 q0 = wp[0];
                float4 q1 = wp[1];
                bf16x8 whi, wlo;
                split8(q0, q1, &whi, &wlo);
                acc = __builtin_amdgcn_mfma_f32_16x16x32_bf16(wlo, xhi[kb], acc, 0, 0, 0);
                acc = __builtin_amdgcn_mfma_f32_16x16x32_bf16(whi, xlo[kb], acc, 0, 0, 0);
                acc = __builtin_amdgcn_mfma_f32_16x16x32_bf16(whi, xhi[kb], acc, 0, 0, 0);
            }
            if (node < n) {
                // lane holds o = 16*tt + 4*g + r for r=0..3 -> quad fq = 4*tt + g
                ushort4 h;
                h.x = f2b_rn(acc[0]);
                h.y = f2b_rn(acc[1]);
                h.z = f2b_rn(acc[2]);
                h.w = f2b_rn(acc[3]);
                yh[(size_t)node * 16 + (tt * 4 + g)] = h;
            }
        }
    }
}

// --- D2: per-bucket deg hist -> dnorm[node] = rsqrt(deg+1) (400KB table) ---
__global__ __launch_bounds__(256) void dnorm_kernel(
    const unsigned int* __restrict__ grec, const int* __restrict__ gcur,
    float* __restrict__ dnorm, int n) {
    __shared__ int lh[BNODES];
    int t = threadIdx.x;
    int b = blockIdx.x;
    size_t base = (size_t)b * CAP;
    int cnt = gcur[b];
    if (cnt > CAP) cnt = CAP;
    if (t < BNODES) lh[t] = 0;
    __syncthreads();
    for (int i = t; i < cnt; i += 256)
        atomicAdd(&lh[grec[base + i] & (BNODES - 1)], 1);
    __syncthreads();
    if (t < BNODES) {
        int node = (b << BSHIFT) + t;
        if (node < n) dnorm[node] = rsqrtf((float)lh[t] + 1.0f);
    }
}

// --- D3: per-bucket fused sort + dnorm-weighted gather (782 x 512thr) ---
__global__ __launch_bounds__(512, 4) void csr_gather_kernel(
    const unsigned int* __restrict__ grec, const int* __restrict__ gcur,
    const ushort4* __restrict__ yh, const float* __restrict__ dnorm,
    const float* __restrict__ bias,
    float4* __restrict__ out, int n) {
    __shared__ unsigned int sorted[CAP];  // 12288 B: src ids grouped by dst
    __shared__ int lh[BNODES];            // hist, then cursor
    __shared__ int ls[BNODES + 1];        // exclusive offsets; ls[128] = cnt
    __shared__ int wtot;
    int t = threadIdx.x;
    int b = blockIdx.x;
    size_t base = (size_t)b * CAP;
    int cnt = gcur[b];
    if (cnt > CAP) cnt = CAP;
    int node0 = b << BSHIFT;

    if (t < BNODES) lh[t] = 0;
    __syncthreads();
    for (int i = t; i < cnt; i += 512)
        atomicAdd(&lh[grec[base + i] & (BNODES - 1)], 1);
    __syncthreads();
    int c = 0, ex = 0;
    if (t < BNODES) {  // waves 0,1: inclusive shfl scan over 128 bins
        c = lh[t];
        int lane64 = t & 63;
        int v = c;
#pragma unroll
        for (int o = 1; o < 64; o <<= 1) {
            int u = __shfl_up(v, o, 64);
            if (lane64 >= o) v += u;
        }
        if (t == 63) wtot = v;
        ex = v - c;
    }
    __syncthreads();
    if (t >= 64 && t < BNODES) ex += wtot;
    if (t < BNODES) {
        ls[t] = ex;
        lh[t] = 0;  // cursor
        if (t == BNODES - 1) ls[BNODES] = ex + c;
    }
    __syncthreads();
    for (int i = t; i < cnt; i += 512) {  // re-read grec (L2-hot), sort into LDS
        unsigned int r = grec[base + i];
        int nd = r & (BNODES - 1);
        int pos = ls[nd] + atomicAdd(&lh[nd], 1);
        sorted[pos] = r >> BSHIFT;
    }
    __syncthreads();

    // ---- gather: wave w handles nodes [w*16, w*16+16) of this bucket ----
    int wave = t >> 6;
    int lane = t & 63;
    int grp = lane >> 4;   // which of 4 concurrent edges
    int fq = lane & 15;    // feature quad
    float4 bb = ((const float4*)bias)[fq];
    for (int i = 0; i < 16; ++i) {
        int nd = wave * 16 + i;
        int node = node0 + nd;
        if (node >= n) break;  // uniform per wave
        int beg = ls[nd];
        int end = ls[nd + 1];
        float dn = rsqrtf((float)(end - beg) + 1.0f);  // deg+1 (self loop)
        float4 acc = {0.f, 0.f, 0.f, 0.f};
        if (grp == 0) {  // self loop term: dn_self == dn (same node)
            ushort4 h = yh[(size_t)node * 16 + fq];
            acc.x = dn * b2f(h.x); acc.y = dn * b2f(h.y);
            acc.z = dn * b2f(h.z); acc.w = dn * b2f(h.w);
        }
        int j = beg + grp;
        // 4x unrolled: four independent row loads in flight per iteration
        for (; j + 12 < end; j += 16) {
            int s0 = (int)sorted[j];
            int s1 = (int)sorted[j + 4];
            int s2 = (int)sorted[j + 8];
            int s3 = (int)sorted[j + 12];
            ushort4 h0 = yh[(size_t)s0 * 16 + fq];  // 128B rows
            ushort4 h1 = yh[(size_t)s1 * 16 + fq];
            ushort4 h2 = yh[(size_t)s2 * 16 + fq];
            ushort4 h3 = yh[(size_t)s3 * 16 + fq];
            float d0 = dnorm[s0];                   // L2-hot 400KB table
            float d1 = dnorm[s1];
            float d2 = dnorm[s2];
            float d3 = dnorm[s3];
            acc.x += d0 * b2f(h0.x); acc.x += d1 * b2f(h1.x);
            acc.x += d2 * b2f(h2.x); acc.x += d3 * b2f(h3.x);
            acc.y += d0 * b2f(h0.y); acc.y += d1 * b2f(h1.y);
            acc.y += d2 * b2f(h2.y); acc.y += d3 * b2f(h3.y);
            acc.z += d0 * b2f(h0.z); acc.z += d1 * b2f(h1.z);
            acc.z += d2 * b2f(h2.z); acc.z += d3 * b2f(h3.z);
            acc.w += d0 * b2f(h0.w); acc.w += d1 * b2f(h1.w);
            acc.w += d2 * b2f(h2.w); acc.w += d3 * b2f(h3.w);
        }
        for (; j < end; j += 4) {  // tail, one per group-stride
            int s = (int)sorted[j];
            ushort4 h = yh[(size_t)s * 16 + fq];
            float d0 = dnorm[s];
            acc.x += d0 * b2f(h.x); acc.y += d0 * b2f(h.y);
            acc.z += d0 * b2f(h.z); acc.w += d0 * b2f(h.w);
        }
        for (int m = 16; m < 64; m <<= 1) {  // reduce 4 edge-groups
            acc.x += __shfl_xor(acc.x, m);
            acc.y += __shfl_xor(acc.y, m);
            acc.z += __shfl_xor(acc.z, m);
            acc.w += __shfl_xor(acc.w, m);
        }
        if (lane < 16) {
            float4 o;
            o.x = acc.x * dn + bb.x;
            o.y = acc.y * dn + bb.y;
            o.z = acc.z * dn + bb.z;
            o.w = acc.w * dn + bb.w;
            out[(size_t)node * 16 + lane] = o;
        }
    }
}

extern "C" void kernel_launch(void* const* d_in, const int* in_sizes, int n_in,
                              void* d_out, int out_size, void* d_ws, size_t ws_size,
                              hipStream_t stream) {
    const float* x    = (const float*)d_in[0];
    const int*   ei   = (const int*)d_in[1];  // [2,E]: src row then dst row
    const float* W    = (const float*)d_in[2];
    const float* bias = (const float*)d_in[3];
    float* out = (float*)d_out;

    int n = in_sizes[0] / 64;
    int e = in_sizes[1] / 2;
    int nbuck = (n + BNODES - 1) / BNODES;  // 782 (<=1024 for scatter smem carve)

    // workspace (256B aligned): gcur | grec | dnorm | yh  (~23 MB)
    auto align = [](size_t v) { return (v + 255) & ~(size_t)255; };
    char* p = (char*)d_ws;
    int* gcur = (int*)p;                    p += align((size_t)nbuck * 4);
    unsigned int* grec = (unsigned int*)p;  p += align((size_t)nbuck * CAP * 4);
    float* dnorm = (float*)p;               p += align((size_t)n * 4);
    ushort4* yh = (ushort4*)p;

    int sblocks = (e + EPB - 1) / EPB;   // 391
    int gblocks = (n + 63) / 64;         // 1563 gemm tiles

    hipMemsetAsync(gcur, 0, (size_t)nbuck * 4, stream);
    fused_gemm_scatter_kernel<<<sblocks + gblocks, 256, 0, stream>>>(
        x, W, yh, ei, gcur, grec, n, e, nbuck, sblocks);
    dnorm_kernel<<<nbuck, 256, 0, stream>>>(grec, gcur, dnorm, n);
    csr_gather_kernel<<<nbuck, 512, 0, stream>>>(grec, gcur, yh, dnorm, bias,
                                                 (float4*)out, n);
}

// Round 7
// 160.318 us; speedup vs baseline: 1.1062x; 1.0180x over previous
//
#include <hip/hip_runtime.h>

// GCN layer: out = (D^-1/2 (A+I) D^-1/2) X W^T + b
// N=100000, E=1600000, D=64.
//
// Round 18: resubmit of r17 (bench infra failed twice; no counter or
// validation evidence against the kernel; source audited -- LDS budgets,
// fragment-index bijection, sync ordering, guards all check out).
//
// r17 rationale: de-fuse + re-absorb normalization.
// r16 post-mortem: total moved only -2.7us despite MFMA gemm. Accounting
// shows the fused dispatch is STILL ~45us -> the scatter branch (never
// individually measured since r0) is its long pole, not the gemm. And the
// gather paid +6us for per-edge dnorm[src] loads (50.2 vs r11's 44.0).
// New structure:
//   D1 scatter standalone (first-ever per-kernel counters for it)
//   D2 gemm_scaled: bucket-aligned (512thr = 128 nodes = 1 bucket):
//      per-bucket LDS deg hist over its own grec region (~2K recs, L2-hot)
//      + split-bf16 MFMA gemm (W staged in LDS as pre-split fragments,
//      once per block) + yh = bf16(acc * rsqrt(deg+1))
//   D3 csr_gather: r11's pre-scaled-row version (measured 44.0us), no
//      dnorm table anywhere.
// MFMA numerics identical to r16 (same fragment map, same split, same
// rounding point as r11) -> absmax stays 0.00390625.
//
// Pipeline: D0 memset gcur | D1 scatter | D2 gemm_scaled | D3 csr_gather

#define BSHIFT 7
#define BNODES 128
#define CAP 3072   // records per bucket region (mean 2046, P(overflow)~1e-90)
#define EPB 4096   // edges per scatter block -> 391 blocks

typedef short bf16x8 __attribute__((ext_vector_type(8)));
typedef float f32x4 __attribute__((ext_vector_type(4)));

__device__ inline unsigned short f2b_rn(float f) {
    unsigned u = __float_as_uint(f);
    unsigned r = u + 0x7FFFu + ((u >> 16) & 1u);
    return (unsigned short)(r >> 16);
}
__device__ inline float b2f(unsigned short h) {
    return __uint_as_float(((unsigned)h) << 16);
}

// split 8 fp32 (two float4) into hi (truncated bf16) + lo (bf16 of residual)
__device__ inline void split8(float4 a, float4 b, bf16x8* hi, bf16x8* lo) {
    float f[8] = {a.x, a.y, a.z, a.w, b.x, b.y, b.z, b.w};
    union U { unsigned u[4]; bf16x8 v; } uh, ul;
#pragma unroll
    for (int i = 0; i < 4; ++i) {
        unsigned u0 = __float_as_uint(f[2 * i]);
        unsigned u1 = __float_as_uint(f[2 * i + 1]);
        uh.u[i] = (u0 >> 16) | (u1 & 0xFFFF0000u);
        float r0 = f[2 * i]     - __uint_as_float(u0 & 0xFFFF0000u);
        float r1 = f[2 * i + 1] - __uint_as_float(u1 & 0xFFFF0000u);
        unsigned v0 = __float_as_uint(r0);
        unsigned v1 = __float_as_uint(r1);
        ul.u[i] = (v0 >> 16) | (v1 & 0xFFFF0000u);
    }
    *hi = uh.v;
    *lo = ul.v;
}

// --- D1: binned scatter into fixed-capacity bucket regions (standalone) ---
__global__ __launch_bounds__(256) void scatter_kernel(
    const int* __restrict__ ei, int* __restrict__ gcur,
    unsigned int* __restrict__ grec, int e, int nbuck) {
    __shared__ unsigned int lrec[EPB];       // 16384 B
    __shared__ unsigned short lbk[EPB];      //  8192 B
    __shared__ int lh[1024];                 //  4096 B (nbuck=782)
    __shared__ int lbase[1024];              //  4096 B
    int t = threadIdx.x;
    for (int i = t; i < nbuck; i += 256) lh[i] = 0;
    __syncthreads();
    int e0 = blockIdx.x * EPB;
    int m = e - e0;
    if (m > EPB) m = EPB;
    for (int i = t; i < m; i += 256) {
        int g = e0 + i;
        int s = ei[g];
        int d = ei[e + g];
        int b = d >> BSHIFT;
        lrec[i] = ((unsigned int)s << BSHIFT) | (unsigned int)(d & (BNODES - 1));
        lbk[i] = (unsigned short)b;
        atomicAdd(&lh[b], 1);
    }
    __syncthreads();
    for (int b = t; b < nbuck; b += 256) {
        int c = lh[b];
        lbase[b] = c ? atomicAdd(&gcur[b], c) : 0;
        lh[b] = 0;  // reuse as local cursor
    }
    __syncthreads();
    for (int i = t; i < m; i += 256) {
        int b = lbk[i];
        int pos = lbase[b] + atomicAdd(&lh[b], 1);
        if (pos < CAP)
            grec[(size_t)b * CAP + pos] = lrec[i];
    }
}

// --- D2: bucket-aligned MFMA gemm + deg hist + pre-scaled bf16 out ---
// Block b = bucket b = nodes [128b, 128b+128); 512 thr = 8 waves x 16 nodes.
__global__ __launch_bounds__(512) void gemm_scaled_kernel(
    const float* __restrict__ x, const float* __restrict__ W,
    ushort4* __restrict__ yh,
    const unsigned int* __restrict__ grec, const int* __restrict__ gcur,
    int n) {
    __shared__ bf16x8 Whi[512];   // 8KB: pre-split W fragments, frag f =
    __shared__ bf16x8 Wlo[512];   // 8KB: ((tt*2+kb)*4+g)*16+jn  (= lane order)
    __shared__ int lh[BNODES];
    int t = threadIdx.x;
    int b = blockIdx.x;
    int node0 = b << BSHIFT;

    if (t < BNODES) lh[t] = 0;
    __syncthreads();

    // deg hist over this bucket's grec region (~2K records, L2/L3-hot)
    size_t base = (size_t)b * CAP;
    int cnt = gcur[b];
    if (cnt > CAP) cnt = CAP;
    for (int i = t; i < cnt; i += 512)
        atomicAdd(&lh[grec[base + i] & (BNODES - 1)], 1);

    // stage split-bf16 W fragments (once per block; 16KB L2-hot reads)
    {
        int tt = t >> 7, kb = (t >> 6) & 1, g = (t >> 4) & 3, jn = t & 15;
        const float4* wp =
            (const float4*)(W + (size_t)(tt * 16 + jn) * 64 + kb * 32 + g * 8);
        bf16x8 hi, lo;
        split8(wp[0], wp[1], &hi, &lo);
        Whi[t] = hi;
        Wlo[t] = lo;
    }
    __syncthreads();

    int wave = t >> 6, lane = t & 63;
    int jn = lane & 15;      // node within wave tile (B-frag / D col)
    int g = lane >> 4;       // k-subgroup: elements k = 8g..8g+7 (+32*kb)
    int node = node0 + wave * 16 + jn;

    // x fragments: hi/lo for kb=0,1
    bf16x8 xhi[2], xlo[2];
#pragma unroll
    for (int kb = 0; kb < 2; ++kb) {
        float4 p0 = {0.f, 0.f, 0.f, 0.f}, p1 = {0.f, 0.f, 0.f, 0.f};
        if (node < n) {
            const float4* xp =
                (const float4*)(x + (size_t)node * 64 + kb * 32 + g * 8);
            p0 = xp[0];
            p1 = xp[1];
        }
        split8(p0, p1, &xhi[kb], &xlo[kb]);
    }

    float dn = rsqrtf((float)lh[wave * 16 + jn] + 1.0f);  // +1 self loop

#pragma unroll
    for (int tt = 0; tt < 4; ++tt) {
        f32x4 acc = {0.f, 0.f, 0.f, 0.f};
#pragma unroll
        for (int kb = 0; kb < 2; ++kb) {
            bf16x8 whi = Whi[(tt * 2 + kb) * 64 + lane];
            bf16x8 wlo = Wlo[(tt * 2 + kb) * 64 + lane];
            acc = __builtin_amdgcn_mfma_f32_16x16x32_bf16(wlo, xhi[kb], acc, 0, 0, 0);
            acc = __builtin_amdgcn_mfma_f32_16x16x32_bf16(whi, xlo[kb], acc, 0, 0, 0);
            acc = __builtin_amdgcn_mfma_f32_16x16x32_bf16(whi, xhi[kb], acc, 0, 0, 0);
        }
        if (node < n) {
            // lane holds o = 16*tt + 4*g + r, r=0..3 -> feature quad 4*tt+g
            ushort4 h;
            h.x = f2b_rn(acc[0] * dn);
            h.y = f2b_rn(acc[1] * dn);
            h.z = f2b_rn(acc[2] * dn);
            h.w = f2b_rn(acc[3] * dn);
            yh[(size_t)node * 16 + (tt * 4 + g)] = h;
        }
    }
}

// --- D3: per-bucket fused sort + gather of pre-scaled rows (r11 version) ---
__global__ __launch_bounds__(512, 4) void csr_gather_kernel(
    const unsigned int* __restrict__ grec, const int* __restrict__ gcur,
    const ushort4* __restrict__ yh, const float* __restrict__ bias,
    float4* __restrict__ out, int n) {
    __shared__ unsigned int sorted[CAP];  // 12288 B: src ids grouped by dst
    __shared__ int lh[BNODES];            // hist, then cursor
    __shared__ int ls[BNODES + 1];        // exclusive offsets; ls[128] = cnt
    __shared__ int wtot;
    int t = threadIdx.x;
    int b = blockIdx.x;
    size_t base = (size_t)b * CAP;
    int cnt = gcur[b];
    if (cnt > CAP) cnt = CAP;
    int node0 = b << BSHIFT;

    if (t < BNODES) lh[t] = 0;
    __syncthreads();
    for (int i = t; i < cnt; i += 512)
        atomicAdd(&lh[grec[base + i] & (BNODES - 1)], 1);
    __syncthreads();
    int c = 0, ex = 0;
    if (t < BNODES) {  // waves 0,1: inclusive shfl scan over 128 bins
        c = lh[t];
        int lane64 = t & 63;
        int v = c;
#pragma unroll
        for (int o = 1; o < 64; o <<= 1) {
            int u = __shfl_up(v, o, 64);
            if (lane64 >= o) v += u;
        }
        if (t == 63) wtot = v;
        ex = v - c;
    }
    __syncthreads();
    if (t >= 64 && t < BNODES) ex += wtot;
    if (t < BNODES) {
        ls[t] = ex;
        lh[t] = 0;  // cursor
        if (t == BNODES - 1) ls[BNODES] = ex + c;
    }
    __syncthreads();
    for (int i = t; i < cnt; i += 512) {  // re-read grec (L2-hot), sort into LDS
        unsigned int r = grec[base + i];
        int nd = r & (BNODES - 1);
        int pos = ls[nd] + atomicAdd(&lh[nd], 1);
        sorted[pos] = r >> BSHIFT;
    }
    __syncthreads();

    // ---- gather: wave w handles nodes [w*16, w*16+16) of this bucket ----
    int wave = t >> 6;
    int lane = t & 63;
    int grp = lane >> 4;   // which of 4 concurrent edges
    int fq = lane & 15;    // feature quad
    float4 bb = ((const float4*)bias)[fq];
    for (int i = 0; i < 16; ++i) {
        int nd = wave * 16 + i;
        int node = node0 + nd;
        if (node >= n) break;  // uniform per wave
        int beg = ls[nd];
        int end = ls[nd + 1];
        float dn = rsqrtf((float)(end - beg) + 1.0f);  // deg+1 (self loop)
        float4 acc = {0.f, 0.f, 0.f, 0.f};
        if (grp == 0) {  // self loop term y'_self (pre-scaled row)
            ushort4 h = yh[(size_t)node * 16 + fq];
            acc.x = b2f(h.x); acc.y = b2f(h.y);
            acc.z = b2f(h.z); acc.w = b2f(h.w);
        }
        int j = beg + grp;
        // 4x unrolled: four independent row loads in flight per iteration
        for (; j + 12 < end; j += 16) {
            int s0 = (int)sorted[j];
            int s1 = (int)sorted[j + 4];
            int s2 = (int)sorted[j + 8];
            int s3 = (int)sorted[j + 12];
            ushort4 h0 = yh[(size_t)s0 * 16 + fq];  // 128B rows
            ushort4 h1 = yh[(size_t)s1 * 16 + fq];
            ushort4 h2 = yh[(size_t)s2 * 16 + fq];
            ushort4 h3 = yh[(size_t)s3 * 16 + fq];
            acc.x += b2f(h0.x) + b2f(h1.x) + b2f(h2.x) + b2f(h3.x);
            acc.y += b2f(h0.y) + b2f(h1.y) + b2f(h2.y) + b2f(h3.y);
            acc.z += b2f(h0.z) + b2f(h1.z) + b2f(h2.z) + b2f(h3.z);
            acc.w += b2f(h0.w) + b2f(h1.w) + b2f(h2.w) + b2f(h3.w);
        }
        for (; j < end; j += 4) {  // tail, one per group-stride
            int s = (int)sorted[j];
            ushort4 h = yh[(size_t)s * 16 + fq];
            acc.x += b2f(h.x); acc.y += b2f(h.y);
            acc.z += b2f(h.z); acc.w += b2f(h.w);
        }
        for (int m = 16; m < 64; m <<= 1) {  // reduce 4 edge-groups
            acc.x += __shfl_xor(acc.x, m);
            acc.y += __shfl_xor(acc.y, m);
            acc.z += __shfl_xor(acc.z, m);
            acc.w += __shfl_xor(acc.w, m);
        }
        if (lane < 16) {
            float4 o;
            o.x = acc.x * dn + bb.x;
            o.y = acc.y * dn + bb.y;
            o.z = acc.z * dn + bb.z;
            o.w = acc.w * dn + bb.w;
            out[(size_t)node * 16 + lane] = o;
        }
    }
}

extern "C" void kernel_launch(void* const* d_in, const int* in_sizes, int n_in,
                              void* d_out, int out_size, void* d_ws, size_t ws_size,
                              hipStream_t stream) {
    const float* x    = (const float*)d_in[0];
    const int*   ei   = (const int*)d_in[1];  // [2,E]: src row then dst row
    const float* W    = (const float*)d_in[2];
    const float* bias = (const float*)d_in[3];
    float* out = (float*)d_out;

    int n = in_sizes[0] / 64;
    int e = in_sizes[1] / 2;
    int nbuck = (n + BNODES - 1) / BNODES;  // 782 (<=1024 for scatter smem)

    // workspace (256B aligned): gcur | grec | yh  (~23 MB)
    auto align = [](size_t v) { return (v + 255) & ~(size_t)255; };
    char* p = (char*)d_ws;
    int* gcur = (int*)p;                    p += align((size_t)nbuck * 4);
    unsigned int* grec = (unsigned int*)p;  p += align((size_t)nbuck * CAP * 4);
    ushort4* yh = (ushort4*)p;

    int sblocks = (e + EPB - 1) / EPB;   // 391

    hipMemsetAsync(gcur, 0, (size_t)nbuck * 4, stream);
    scatter_kernel<<<sblocks, 256, 0, stream>>>(ei, gcur, grec, e, nbuck);
    gemm_scaled_kernel<<<nbuck, 512, 0, stream>>>(x, W, yh, grec, gcur, n);
    csr_gather_kernel<<<nbuck, 512, 0, stream>>>(grec, gcur, yh, bias,
                                                 (float4*)out, n);
}